// Round 8
// baseline (351.843 us; speedup 1.0000x reference)
//
#include <hip/hip_runtime.h>

// TropicalMultiHeadAttention — MI355X (gfx950)  Round 15
// B=2, L=1024, D=1024, H=16, dk=64, SCALE=0.125; causal (mask input ignored).
// Outputs: out (2,1024,1024) f32 ++ attn (2,16,1024,1024) f32.
//
// R15 vs R14 (298.9us best; scores 101us):
//  * DIAGNOSIS: R14 scores VGPR=56 < 64 needed for kr1+kr2 => compiler fissioned the
//    q-loop (load kr1 / 16 iters / load kr2 / 16 iters), so 8 ds_read_b128 Q-broadcasts
//    amortize over ONE key -> ~1.7 LDS-cyc/pair -> LDS-issue-bound (~46us of phase 1).
//  * FIX: thread owns 4 consecutive keys 4t..4t+3 (one pass, exact guard since q0+16
//    is a multiple of 4); K rows pinned in 128 VGPRs via asm "+v" at one point;
//    amdgpu_waves_per_eu(2,2) gives the allocator a 256-VGPR budget (no remat/spill);
//    ONE fused i-loop interleaves all 4 keys (fission unprofitable).  Q-broadcast now
//    amortized 4x; score write = one ds_write_b64 per (q,thread).
//  * softmax/PV/attn phases + all other kernels = R14 verbatim.
//  Failure signatures: VGPR<=100 -> remat (R9); FETCH/WRITE >200MB -> spill (R11).
//  Pipeline: cvt, gemm_qkv(+gate), scores_fused, gemm_out — 4 launches.

typedef _Float16 f16;
typedef __attribute__((ext_vector_type(2))) _Float16 h2;
typedef __attribute__((ext_vector_type(8))) _Float16 f16x8;
typedef __attribute__((ext_vector_type(4))) float f32x4;
typedef __attribute__((ext_vector_type(4))) unsigned int u32x4;

__device__ inline f32x4 mfma_f16(f16x8 a, f16x8 b, f32x4 c) {
    return __builtin_amdgcn_mfma_f32_16x16x32_f16(a, b, c, 0, 0, 0);
}

__device__ inline void async_copy16(const f16* g, f16* l) {
    __builtin_amdgcn_global_load_lds((const __attribute__((address_space(1))) void*)g,
                                     (__attribute__((address_space(3))) void*)l, 16, 0, 0);
}

__device__ inline float dot2acc(h2 a, h2 b, float c) {
#if __has_builtin(__builtin_amdgcn_fdot2)
    return __builtin_amdgcn_fdot2(a, b, c, false);
#else
    c = fmaf((float)a[0], (float)b[0], c);
    return fmaf((float)a[1], (float)b[1], c);
#endif
}

// ---------------------------------------------------------------- all f32->f16 converts, one kernel
// ranges (float4 units): x 524288 | Wq 262144 | Wk 262144 | Wv 262144 | Wo 262144 |
//                        Wg 4096 | zero-pad 12288  -> total 1589248 = 6208 blocks
__global__ __launch_bounds__(256) void cvt_all(const float* __restrict__ x,
                                               const float* __restrict__ Wq,
                                               const float* __restrict__ Wk,
                                               const float* __restrict__ Wv,
                                               const float* __restrict__ Wo,
                                               const float* __restrict__ Wg,
                                               f16* __restrict__ x16,
                                               f16* __restrict__ w16,
                                               f16* __restrict__ wo16) {
    int i = blockIdx.x * 256 + threadIdx.x;
    if (i >= 1576960) {  // zero-fill pad rows 3088..3135 of w16
        int off = i - 1576960;  // 0..12287
        *(uint2*)(w16 + (size_t)(3088 << 10) + (size_t)off * 4) = make_uint2(0u, 0u);
        return;
    }
    const float* s;
    f16* d;
    int off;
    if (i < 524288)       { s = x;  d = x16;                        off = i; }
    else if (i < 786432)  { s = Wq; d = w16;                        off = i - 524288; }
    else if (i < 1048576) { s = Wk; d = w16 + (1 << 20);            off = i - 786432; }
    else if (i < 1310720) { s = Wv; d = w16 + (2 << 20);            off = i - 1048576; }
    else if (i < 1572864) { s = Wo; d = wo16;                       off = i - 1310720; }
    else                  { s = Wg; d = w16 + (size_t)(3072 << 10); off = i - 1572864; }
    float4 v = *(const float4*)(s + (size_t)off * 4);
    f16 o[4] = {(f16)v.x, (f16)v.y, (f16)v.z, (f16)v.w};
    *(uint2*)(d + (size_t)off * 4) = *(uint2*)o;
}

// ---------------------------------------------------------------- 128x64 MFMA GEMM  C = A @ B^T + bias
// R7-proven. VTR: V column-tiles (2048<=n0<3072) write V^T to vt.
// GATE: n0>=3072 col-tile computes x@Wg^T -> sigmoid(acc+bg) -> gbuf (cols 0..15 valid).
template <bool OUT16, bool VTR, bool GATE>
__global__ __launch_bounds__(256) void gemm128(const f16* __restrict__ A,
                                               const f16* __restrict__ B,
                                               void* __restrict__ Cv,
                                               const float* __restrict__ b0,
                                               const float* __restrict__ b1,
                                               const float* __restrict__ b2,
                                               const float* __restrict__ bgv,
                                               f16* __restrict__ vt,
                                               float* __restrict__ gbuf,
                                               int K, int lda, int ldb, int ldc) {
    __shared__ f16 At[128 * 32];
    __shared__ f16 Bt[64 * 32];
    const int t = threadIdx.x;
    const int m0 = blockIdx.y * 128, n0 = blockIdx.x * 64;
    const int wave = t >> 6, lane = t & 63;
    const int l16 = lane & 15, quad = lane >> 4;
    const int wm = (wave >> 1) * 64, wn = (wave & 1) * 32;
    const int sr = t >> 2, sc = (t & 3) * 8;
    f32x4 acc[4][2] = {};
    for (int k0 = 0; k0 < K; k0 += 32) {
        __syncthreads();
#pragma unroll
        for (int i = 0; i < 2; ++i)
            async_copy16(A + (size_t)(m0 + sr + i * 64) * lda + k0 + sc, &At[t * 8 + i * 2048]);
        async_copy16(B + (size_t)(n0 + sr) * ldb + k0 + sc, &Bt[t * 8]);
        __syncthreads();
        f16x8 af[4], bfr[2];
#pragma unroll
        for (int i = 0; i < 4; ++i)
            af[i] = *(const f16x8*)&At[(wm + i * 16 + l16) * 32 + quad * 8];
#pragma unroll
        for (int i = 0; i < 2; ++i)
            bfr[i] = *(const f16x8*)&Bt[(wn + i * 16 + l16) * 32 + quad * 8];
#pragma unroll
        for (int mi = 0; mi < 4; ++mi)
#pragma unroll
            for (int ni = 0; ni < 2; ++ni)
                acc[mi][ni] = mfma_f16(af[mi], bfr[ni], acc[mi][ni]);
    }
#pragma unroll
    for (int mi = 0; mi < 4; ++mi) {
#pragma unroll
        for (int ni = 0; ni < 2; ++ni) {
            int gcol = n0 + wn + ni * 16 + l16;
            if (GATE && n0 >= 3072) {
                // gate tile: cols 3072..3087 valid (Wg rows 0..15), rest zero-pad
                int hd = gcol - 3072;
                if (hd < 16) {
                    float bias = bgv[hd];
#pragma unroll
                    for (int rg = 0; rg < 4; ++rg) {
                        int grow = m0 + wm + mi * 16 + quad * 4 + rg;
                        float v = acc[mi][ni][rg] + bias;
                        gbuf[(size_t)grow * 16 + hd] = 1.0f / (1.0f + __expf(-v));
                    }
                }
            } else if (VTR && n0 >= 2048) {
                const float* bp = b2;
                float bias = bp[gcol & 1023];
                int hd = gcol - 2048;
                int h = hd >> 6, d = hd & 63;
                int k0r = m0 + wm + mi * 16 + quad * 4;  // 4 consecutive k
                int b = k0r >> 10;
                f16 o4[4];
#pragma unroll
                for (int rg = 0; rg < 4; ++rg) o4[rg] = (f16)(acc[mi][ni][rg] + bias);
                *(uint2*)&vt[((size_t)((b * 16 + h) * 64 + d)) * 1024 + (k0r & 1023)] =
                    *(uint2*)o4;
            } else {
                const float* bp = (gcol < 1024) ? b0 : (gcol < 2048 ? b1 : b2);
                float bias = bp[gcol & 1023];
#pragma unroll
                for (int rg = 0; rg < 4; ++rg) {
                    int grow = m0 + wm + mi * 16 + quad * 4 + rg;
                    float v = acc[mi][ni][rg] + bias;
                    if (OUT16)
                        ((f16*)Cv)[(size_t)grow * ldc + gcol] = (f16)v;
                    else
                        ((float*)Cv)[(size_t)grow * ldc + gcol] = v;
                }
            }
        }
    }
}

// ---------------------------------------------------------------- scores + softmax + attn + PV (fused)
// Block: (b,h,16-row q-tile).
// Phase 1: thread owns keys 4t..4t+3 (all in regs, pinned); q-loop reads Q via broadcast
//          ds_read_b128 (amortized over 4 keys); fused 4-key tropical+dot inner loop;
//          one ds_write_b64 of 4 f16 scores per (q,thread).
// Phase 2: causal softmax (R14 verbatim).  Phase 3: PV via MFMA (R14 verbatim).
__global__ __launch_bounds__(256) __attribute__((amdgpu_waves_per_eu(2, 2)))
void scores_fused(const f16* __restrict__ qkv16,
                  const f16* __restrict__ vt16,
                  const float* __restrict__ gbuf,
                  const float* __restrict__ log_temps,
                  float* __restrict__ attn,
                  f16* __restrict__ oh) {
    __shared__ f16 Qs[16][64];
    __shared__ f16 Ssm[16][1032];  // stride 1032: spreads PV a-frag rows across banks
    __shared__ float gsm[16];
    const int t = threadIdx.x;
    const int qt = 63 - (blockIdx.x >> 5);  // heavy tiles first
    const int bh = blockIdx.x & 31;
    const int b = bh & 1, h = bh >> 1;
    const int q0 = qt << 4;
    {
        int rr = t >> 4, cc = (t & 15) * 4;
        *(uint2*)&Qs[rr][cc] =
            *(const uint2*)(qkv16 + (size_t)(b * 1024 + q0 + rr) * 3072 + h * 64 + cc);
    }
    if (t < 16) gsm[t] = gbuf[(size_t)(b * 1024 + q0 + t) * 16 + h];
    float tau = __expf(log_temps[h]);
    tau = fminf(fmaxf(tau, 0.02f), 10.0f);
    const float invtau = 1.0f / tau;
    __syncthreads();

    const int qmax = q0 + 15;

    // ---- phase 1: tropical+dot, 4 consecutive keys per thread, single pass
    {
        const int k0 = t * 4;
        if (k0 <= qmax) {  // q0+16 is a multiple of 4 => all 4 keys valid together
            h2 kr0[32], kr1[32], kr2[32], kr3[32];
            const f16* Kp = qkv16 + (size_t)(b * 1024 + k0) * 3072 + 1024 + h * 64;
#pragma unroll
            for (int i = 0; i < 8; ++i) {
                *(f16x8*)&kr0[i * 4] = *(const f16x8*)(Kp + i * 8);
                *(f16x8*)&kr1[i * 4] = *(const f16x8*)(Kp + 3072 + i * 8);
                *(f16x8*)&kr2[i * 4] = *(const f16x8*)(Kp + 6144 + i * 8);
                *(f16x8*)&kr3[i * 4] = *(const f16x8*)(Kp + 9216 + i * 8);
            }
            // pin all 128 K-registers live at one point: forbids remat/sinking (R9 failure)
#pragma unroll
            for (int j = 0; j < 8; ++j) {
                asm volatile("" : "+v"(*(u32x4*)&kr0[j * 4]), "+v"(*(u32x4*)&kr1[j * 4]),
                                  "+v"(*(u32x4*)&kr2[j * 4]), "+v"(*(u32x4*)&kr3[j * 4]));
            }
            for (int q = 0; q < 16; ++q) {
                h2 qr[32];
#pragma unroll
                for (int i = 0; i < 8; ++i)
                    *(f16x8*)&qr[i * 4] = *(const f16x8*)&Qs[q][i * 8];  // broadcast
                const float g = gsm[q];
                const float gi = 1.0f - g;
                h2 ma0 = qr[0] + kr0[0], mb0 = qr[1] + kr0[1];
                h2 ma1 = qr[0] + kr1[0], mb1 = qr[1] + kr1[1];
                h2 ma2 = qr[0] + kr2[0], mb2 = qr[1] + kr2[1];
                h2 ma3 = qr[0] + kr3[0], mb3 = qr[1] + kr3[1];
                float da0 = dot2acc(qr[0], kr0[0], 0.f), db0 = dot2acc(qr[1], kr0[1], 0.f);
                float da1 = dot2acc(qr[0], kr1[0], 0.f), db1 = dot2acc(qr[1], kr1[1], 0.f);
                float da2 = dot2acc(qr[0], kr2[0], 0.f), db2 = dot2acc(qr[1], kr2[1], 0.f);
                float da3 = dot2acc(qr[0], kr3[0], 0.f), db3 = dot2acc(qr[1], kr3[1], 0.f);
#pragma unroll
                for (int i = 2; i < 32; i += 2) {
                    h2 qa = qr[i], qb = qr[i + 1];
                    ma0 = __builtin_elementwise_max(ma0, qa + kr0[i]);
                    mb0 = __builtin_elementwise_max(mb0, qb + kr0[i + 1]);
                    da0 = dot2acc(qa, kr0[i], da0);
                    db0 = dot2acc(qb, kr0[i + 1], db0);
                    ma1 = __builtin_elementwise_max(ma1, qa + kr1[i]);
                    mb1 = __builtin_elementwise_max(mb1, qb + kr1[i + 1]);
                    da1 = dot2acc(qa, kr1[i], da1);
                    db1 = dot2acc(qb, kr1[i + 1], db1);
                    ma2 = __builtin_elementwise_max(ma2, qa + kr2[i]);
                    mb2 = __builtin_elementwise_max(mb2, qb + kr2[i + 1]);
                    da2 = dot2acc(qa, kr2[i], da2);
                    db2 = dot2acc(qb, kr2[i + 1], db2);
                    ma3 = __builtin_elementwise_max(ma3, qa + kr3[i]);
                    mb3 = __builtin_elementwise_max(mb3, qb + kr3[i + 1]);
                    da3 = dot2acc(qa, kr3[i], da3);
                    db3 = dot2acc(qb, kr3[i + 1], db3);
                }
                f16 o4[4];
                {
                    h2 tc = __builtin_elementwise_max(ma0, mb0);
                    float tm = fmaxf((float)tc[0], (float)tc[1]);
                    o4[0] = (f16)((g * tm + gi * (da0 + db0)) * 0.125f);
                }
                {
                    h2 tc = __builtin_elementwise_max(ma1, mb1);
                    float tm = fmaxf((float)tc[0], (float)tc[1]);
                    o4[1] = (f16)((g * tm + gi * (da1 + db1)) * 0.125f);
                }
                {
                    h2 tc = __builtin_elementwise_max(ma2, mb2);
                    float tm = fmaxf((float)tc[0], (float)tc[1]);
                    o4[2] = (f16)((g * tm + gi * (da2 + db2)) * 0.125f);
                }
                {
                    h2 tc = __builtin_elementwise_max(ma3, mb3);
                    float tm = fmaxf((float)tc[0], (float)tc[1]);
                    o4[3] = (f16)((g * tm + gi * (da3 + db3)) * 0.125f);
                }
                *(uint2*)&Ssm[q][k0] = *(uint2*)o4;
            }
        }
    }
    __syncthreads();

    const int lane = t & 63, w = t >> 6;
    const int l16 = lane & 15, quad = lane >> 4;
#pragma unroll
    for (int j = 0; j < 4; ++j) {
        int q = w * 4 + j;
        int qg = q0 + q;
        float m = -1e30f;
        for (int k = lane; k <= qg; k += 64) m = fmaxf(m, (float)Ssm[q][k]);
#pragma unroll
        for (int o = 32; o > 0; o >>= 1) m = fmaxf(m, __shfl_xor(m, o));
        float ssum = 0.f;
        for (int k = lane; k <= qg; k += 64) {
            float e = __expf(((float)Ssm[q][k] - m) * invtau);
            Ssm[q][k] = (f16)e;
            ssum += e;
        }
#pragma unroll
        for (int o = 32; o > 0; o >>= 1) ssum += __shfl_xor(ssum, o);
        float inv = 1.0f / ssum;
        float* orow = attn + ((size_t)((b * 16 + h) * 1024 + qg) << 10);
        for (int k = lane; k < 1024; k += 64) {
            float val = (k <= qg) ? (float)Ssm[q][k] * inv : 0.0f;
            orow[k] = val;
            Ssm[q][k] = (f16)val;  // normalized P (zeros above diag) for PV
        }
    }
    __syncthreads();

    // Phase 3: O(16x64) = P(16x1024) @ V(1024x64); wave w owns d-tile [w*16, w*16+16)
    {
        const int dw = w * 16;
        f32x4 acc = {};
        const int nkt = (q0 + 47) >> 5;  // ceil((qmax+1)/32)
        const f16* Vb = vt16 + ((size_t)((b * 16 + h) * 64 + dw + l16)) * 1024 + quad * 8;
#pragma unroll 4
        for (int kt = 0; kt < nkt; ++kt) {
            const int kb = kt << 5;
            f16x8 a = *(const f16x8*)&Ssm[l16][kb + quad * 8];
            f16x8 bf = *(const f16x8*)(Vb + kb);
            acc = mfma_f16(a, bf, acc);
        }
#pragma unroll
        for (int rg = 0; rg < 4; ++rg)
            oh[(size_t)(b * 1024 + q0 + quad * 4 + rg) * 1024 + h * 64 + dw + l16] =
                (f16)acc[rg];
    }
}

// ----------------------------------------------------------------
extern "C" void kernel_launch(void* const* d_in, const int* in_sizes, int n_in,
                              void* d_out, int out_size, void* d_ws, size_t ws_size,
                              hipStream_t stream) {
    const float* x  = (const float*)d_in[0];
    const float* Wq = (const float*)d_in[2];
    const float* bq = (const float*)d_in[3];
    const float* Wk = (const float*)d_in[4];
    const float* bk = (const float*)d_in[5];
    const float* Wv = (const float*)d_in[6];
    const float* bv = (const float*)d_in[7];
    const float* Wo = (const float*)d_in[8];
    const float* bo = (const float*)d_in[9];
    const float* Wg = (const float*)d_in[10];
    const float* bg = (const float*)d_in[11];
    const float* lt = (const float*)d_in[12];
    float* out = (float*)d_out;
    float* attn = out + (size_t)2 * 1024 * 1024;

    char* ws = (char*)d_ws;
    const size_t KB = (size_t)1 << 10;
    f16*   x16   = (f16*)ws;                     // 4096 KB (2048x1024)
    f16*   w16   = (f16*)(ws + 4096 * KB);       // 6272 KB (Wq|Wk|Wv|Wg-pad 3136x1024)
    f16*   wo16  = (f16*)(ws + 10368 * KB);      // 2048 KB
    f16*   qkv16 = (f16*)(ws + 12416 * KB);      // 12288 KB (Q,K used; V third unused)
    f16*   vt16  = (f16*)(ws + 24704 * KB);      // 4096 KB (V^T per (b*16+h))
    float* gbuf  = (float*)(ws + 28800 * KB);    // 128 KB
    f16*   oh16  = (f16*)(ws + 28928 * KB);      // 4096 KB — total ~32.3 MiB

    cvt_all<<<6208, 256, 0, stream>>>(x, Wq, Wk, Wv, Wo, Wg, x16, w16, wo16);
    gemm128<true, true, true><<<dim3(49, 16), 256, 0, stream>>>(
        x16, w16, qkv16, bq, bk, bv, bg, vt16, gbuf, 1024, 1024, 1024, 3072);
    scores_fused<<<2048, 256, 0, stream>>>(qkv16, vt16, gbuf, lt, attn, oh16);
    gemm128<false, false, false><<<dim3(16, 16), 256, 0, stream>>>(
        oh16, wo16, out, bo, bo, bo, nullptr, nullptr, nullptr, 1024, 1024, 1024, 1024);
}

// Round 9
// 303.270 us; speedup vs baseline: 1.1602x; 1.1602x over previous
//
#include <hip/hip_runtime.h>

// TropicalMultiHeadAttention — MI355X (gfx950)  Round 16
// B=2, L=1024, D=1024, H=16, dk=64, SCALE=0.125; causal (mask input ignored).
// Outputs: out (2,1024,1024) f32 ++ attn (2,16,1024,1024) f32.
//
// R16 = R14 pipeline (298.9us best) + R10's scores VALU cut, WITHOUT R10's confound:
//  * phase 0.5: dot scores via MFMA -> Ssm f16 (R10-proven, passed 3x; ~3us, MfmaUtil 1.4%)
//  * phase 1: R14's exact 2-key/thread mapping, minus the 32 v_dot2 per pair (-1/3 VALU,
//    R10-measured busy 73->53us); dot read back from Ssm (scalar, 2-way aliasing = free)
//  * R10's regression (124us) attributed to its FUSED GATE re-reading x 16x (FETCH 26MB,
//    serial startup) — gone since R14 (gate in gemm_qkv).  This combo is untested.
//  * Qs stride 64->80: phase-0.5 Q-frag reads 16-way -> 4-way bank conflict; phase-1
//    broadcast reads are stride-independent.
//  * everything else R14 verbatim.  R15 lesson: occupancy >= 16 waves/CU is sacred;
//    VGPR-residency tricks that halve it lose (158us @ 21% occ).
//  Pipeline: cvt, gemm_qkv(+gate), scores_fused, gemm_out — 4 launches.

typedef _Float16 f16;
typedef __attribute__((ext_vector_type(2))) _Float16 h2;
typedef __attribute__((ext_vector_type(8))) _Float16 f16x8;
typedef __attribute__((ext_vector_type(4))) float f32x4;

__device__ inline f32x4 mfma_f16(f16x8 a, f16x8 b, f32x4 c) {
    return __builtin_amdgcn_mfma_f32_16x16x32_f16(a, b, c, 0, 0, 0);
}

__device__ inline void async_copy16(const f16* g, f16* l) {
    __builtin_amdgcn_global_load_lds((const __attribute__((address_space(1))) void*)g,
                                     (__attribute__((address_space(3))) void*)l, 16, 0, 0);
}

// ---------------------------------------------------------------- all f32->f16 converts, one kernel
// ranges (float4 units): x 524288 | Wq 262144 | Wk 262144 | Wv 262144 | Wo 262144 |
//                        Wg 4096 | zero-pad 12288  -> total 1589248 = 6208 blocks
__global__ __launch_bounds__(256) void cvt_all(const float* __restrict__ x,
                                               const float* __restrict__ Wq,
                                               const float* __restrict__ Wk,
                                               const float* __restrict__ Wv,
                                               const float* __restrict__ Wo,
                                               const float* __restrict__ Wg,
                                               f16* __restrict__ x16,
                                               f16* __restrict__ w16,
                                               f16* __restrict__ wo16) {
    int i = blockIdx.x * 256 + threadIdx.x;
    if (i >= 1576960) {  // zero-fill pad rows 3088..3135 of w16
        int off = i - 1576960;  // 0..12287
        *(uint2*)(w16 + (size_t)(3088 << 10) + (size_t)off * 4) = make_uint2(0u, 0u);
        return;
    }
    const float* s;
    f16* d;
    int off;
    if (i < 524288)       { s = x;  d = x16;                        off = i; }
    else if (i < 786432)  { s = Wq; d = w16;                        off = i - 524288; }
    else if (i < 1048576) { s = Wk; d = w16 + (1 << 20);            off = i - 786432; }
    else if (i < 1310720) { s = Wv; d = w16 + (2 << 20);            off = i - 1048576; }
    else if (i < 1572864) { s = Wo; d = wo16;                       off = i - 1310720; }
    else                  { s = Wg; d = w16 + (size_t)(3072 << 10); off = i - 1572864; }
    float4 v = *(const float4*)(s + (size_t)off * 4);
    f16 o[4] = {(f16)v.x, (f16)v.y, (f16)v.z, (f16)v.w};
    *(uint2*)(d + (size_t)off * 4) = *(uint2*)o;
}

// ---------------------------------------------------------------- 128x64 MFMA GEMM  C = A @ B^T + bias
// R7-proven. VTR: V column-tiles (2048<=n0<3072) write V^T to vt.
// GATE: n0>=3072 col-tile computes x@Wg^T -> sigmoid(acc+bg) -> gbuf (cols 0..15 valid).
template <bool OUT16, bool VTR, bool GATE>
__global__ __launch_bounds__(256) void gemm128(const f16* __restrict__ A,
                                               const f16* __restrict__ B,
                                               void* __restrict__ Cv,
                                               const float* __restrict__ b0,
                                               const float* __restrict__ b1,
                                               const float* __restrict__ b2,
                                               const float* __restrict__ bgv,
                                               f16* __restrict__ vt,
                                               float* __restrict__ gbuf,
                                               int K, int lda, int ldb, int ldc) {
    __shared__ f16 At[128 * 32];
    __shared__ f16 Bt[64 * 32];
    const int t = threadIdx.x;
    const int m0 = blockIdx.y * 128, n0 = blockIdx.x * 64;
    const int wave = t >> 6, lane = t & 63;
    const int l16 = lane & 15, quad = lane >> 4;
    const int wm = (wave >> 1) * 64, wn = (wave & 1) * 32;
    const int sr = t >> 2, sc = (t & 3) * 8;
    f32x4 acc[4][2] = {};
    for (int k0 = 0; k0 < K; k0 += 32) {
        __syncthreads();
#pragma unroll
        for (int i = 0; i < 2; ++i)
            async_copy16(A + (size_t)(m0 + sr + i * 64) * lda + k0 + sc, &At[t * 8 + i * 2048]);
        async_copy16(B + (size_t)(n0 + sr) * ldb + k0 + sc, &Bt[t * 8]);
        __syncthreads();
        f16x8 af[4], bfr[2];
#pragma unroll
        for (int i = 0; i < 4; ++i)
            af[i] = *(const f16x8*)&At[(wm + i * 16 + l16) * 32 + quad * 8];
#pragma unroll
        for (int i = 0; i < 2; ++i)
            bfr[i] = *(const f16x8*)&Bt[(wn + i * 16 + l16) * 32 + quad * 8];
#pragma unroll
        for (int mi = 0; mi < 4; ++mi)
#pragma unroll
            for (int ni = 0; ni < 2; ++ni)
                acc[mi][ni] = mfma_f16(af[mi], bfr[ni], acc[mi][ni]);
    }
#pragma unroll
    for (int mi = 0; mi < 4; ++mi) {
#pragma unroll
        for (int ni = 0; ni < 2; ++ni) {
            int gcol = n0 + wn + ni * 16 + l16;
            if (GATE && n0 >= 3072) {
                // gate tile: cols 3072..3087 valid (Wg rows 0..15), rest zero-pad
                int hd = gcol - 3072;
                if (hd < 16) {
                    float bias = bgv[hd];
#pragma unroll
                    for (int rg = 0; rg < 4; ++rg) {
                        int grow = m0 + wm + mi * 16 + quad * 4 + rg;
                        float v = acc[mi][ni][rg] + bias;
                        gbuf[(size_t)grow * 16 + hd] = 1.0f / (1.0f + __expf(-v));
                    }
                }
            } else if (VTR && n0 >= 2048) {
                const float* bp = b2;
                float bias = bp[gcol & 1023];
                int hd = gcol - 2048;
                int h = hd >> 6, d = hd & 63;
                int k0r = m0 + wm + mi * 16 + quad * 4;  // 4 consecutive k
                int b = k0r >> 10;
                f16 o4[4];
#pragma unroll
                for (int rg = 0; rg < 4; ++rg) o4[rg] = (f16)(acc[mi][ni][rg] + bias);
                *(uint2*)&vt[((size_t)((b * 16 + h) * 64 + d)) * 1024 + (k0r & 1023)] =
                    *(uint2*)o4;
            } else {
                const float* bp = (gcol < 1024) ? b0 : (gcol < 2048 ? b1 : b2);
                float bias = bp[gcol & 1023];
#pragma unroll
                for (int rg = 0; rg < 4; ++rg) {
                    int grow = m0 + wm + mi * 16 + quad * 4 + rg;
                    float v = acc[mi][ni][rg] + bias;
                    if (OUT16)
                        ((f16*)Cv)[(size_t)grow * ldc + gcol] = (f16)v;
                    else
                        ((float*)Cv)[(size_t)grow * ldc + gcol] = v;
                }
            }
        }
    }
}

// ---------------------------------------------------------------- scores + softmax + attn + PV (fused)
// Block: (b,h,16-row q-tile).
// Phase 0:   Q tile -> LDS (stride 80); gsm from gbuf.
// Phase 0.5: Ssm[q][k] = f16 dot(Q[q],K[k]) via MFMA (A=K rows, B=Q rows; D col=q=l16,
//            row=k=kb+quad*4+rg).  Wave w covers kb = w*16, w*16+64, ...
// Phase 1:   R14 mapping (2 keys/thread/pass, K rows in regs for all 16 q's, Q broadcast
//            ds_read); tropical pk-add/pk-max only (dot from Ssm); mix; overwrite Ssm.
// Phase 2:   causal softmax; attn f32 out + normalized P f16 to Ssm (R14 verbatim).
// Phase 3:   O = P @ V via MFMA from Ssm + L2-hot vt16 (R14 verbatim).
__global__ __launch_bounds__(256) void scores_fused(const f16* __restrict__ qkv16,
                                                    const f16* __restrict__ vt16,
                                                    const float* __restrict__ gbuf,
                                                    const float* __restrict__ log_temps,
                                                    float* __restrict__ attn,
                                                    f16* __restrict__ oh) {
    __shared__ f16 Qs[16][80];     // stride 80: phase-0.5 frag reads 4-way, not 16-way
    __shared__ f16 Ssm[16][1032];  // stride 1032: spreads PV a-frag rows across banks
    __shared__ float gsm[16];
    const int t = threadIdx.x;
    const int qt = 63 - (blockIdx.x >> 5);  // heavy tiles first
    const int bh = blockIdx.x & 31;
    const int b = bh & 1, h = bh >> 1;
    const int q0 = qt << 4;
    const int lane = t & 63, w = t >> 6;
    const int l16 = lane & 15, quad = lane >> 4;
    {
        int rr = t >> 4, cc = (t & 15) * 4;
        *(uint2*)&Qs[rr][cc] =
            *(const uint2*)(qkv16 + (size_t)(b * 1024 + q0 + rr) * 3072 + h * 64 + cc);
    }
    if (t < 16) gsm[t] = gbuf[(size_t)(b * 1024 + q0 + t) * 16 + h];
    float tau = __expf(log_temps[h]);
    tau = fminf(fmaxf(tau, 0.02f), 10.0f);
    const float invtau = 1.0f / tau;
    __syncthreads();

    const int qmax = q0 + 15;

    // ---- phase 0.5: dot scores via MFMA -> Ssm (f16). Wave w: key-tiles w, w+4, ...
    {
        f16x8 qf0 = *(const f16x8*)&Qs[l16][quad * 8];
        f16x8 qf1 = *(const f16x8*)&Qs[l16][32 + quad * 8];
        const f16* Kb = qkv16 + (size_t)(b * 1024 + l16) * 3072 + 1024 + h * 64 + quad * 8;
        for (int kb = w * 16; kb <= qmax; kb += 64) {
            f16x8 kf0 = *(const f16x8*)(Kb + (size_t)kb * 3072);
            f16x8 kf1 = *(const f16x8*)(Kb + (size_t)kb * 3072 + 32);
            f32x4 acc = {};
            acc = mfma_f16(kf0, qf0, acc);
            acc = mfma_f16(kf1, qf1, acc);
            f16 o4[4];
#pragma unroll
            for (int rg = 0; rg < 4; ++rg) o4[rg] = (f16)acc[rg];
            *(uint2*)&Ssm[l16][kb + quad * 4] = *(uint2*)o4;  // q=l16, k=kb+quad*4+rg
        }
    }
    __syncthreads();

    // ---- phase 1: tropical max + mix (R14 mapping, dot from Ssm)
    {
        const int npass = (qmax >> 9) + 1;  // 512-key passes
        for (int p = 0; p < npass; ++p) {
            const int k1 = (p << 9) + t;
            const int k2 = k1 + 256;
            const bool a1 = (k1 <= qmax), a2 = (k2 <= qmax);
            if (a1) {
                const f16* Kp1 = qkv16 + (size_t)(b * 1024 + k1) * 3072 + 1024 + h * 64;
                h2 kr1[32], kr2[32];
#pragma unroll
                for (int i = 0; i < 8; ++i) *(f16x8*)&kr1[i * 4] = ((const f16x8*)Kp1)[i];
                if (a2) {
                    const f16* Kp2 = qkv16 + (size_t)(b * 1024 + k2) * 3072 + 1024 + h * 64;
#pragma unroll
                    for (int i = 0; i < 8; ++i) *(f16x8*)&kr2[i * 4] = ((const f16x8*)Kp2)[i];
                }
#pragma unroll 2
                for (int q = 0; q < 16; ++q) {
                    h2 qr[32];
#pragma unroll
                    for (int i = 0; i < 8; ++i)
                        *(f16x8*)&qr[i * 4] = *(const f16x8*)&Qs[q][i * 8];  // broadcast
                    const float g = gsm[q];
                    {
                        float dot = (float)Ssm[q][k1];
                        h2 ta = qr[0] + kr1[0], tb = qr[1] + kr1[1];
#pragma unroll
                        for (int i = 2; i < 32; i += 2) {
                            ta = __builtin_elementwise_max(ta, qr[i] + kr1[i]);
                            tb = __builtin_elementwise_max(tb, qr[i + 1] + kr1[i + 1]);
                        }
                        h2 tc = __builtin_elementwise_max(ta, tb);
                        float tm = fmaxf((float)tc[0], (float)tc[1]);
                        Ssm[q][k1] = (f16)((g * tm + (1.0f - g) * dot) * 0.125f);
                    }
                    if (a2) {
                        float dot = (float)Ssm[q][k2];
                        h2 ta = qr[0] + kr2[0], tb = qr[1] + kr2[1];
#pragma unroll
                        for (int i = 2; i < 32; i += 2) {
                            ta = __builtin_elementwise_max(ta, qr[i] + kr2[i]);
                            tb = __builtin_elementwise_max(tb, qr[i + 1] + kr2[i + 1]);
                        }
                        h2 tc = __builtin_elementwise_max(ta, tb);
                        float tm = fmaxf((float)tc[0], (float)tc[1]);
                        Ssm[q][k2] = (f16)((g * tm + (1.0f - g) * dot) * 0.125f);
                    }
                }
            }
        }
    }
    __syncthreads();

    // ---- phase 2: causal softmax; attn (f32) out + normalized P (f16) back to Ssm
#pragma unroll
    for (int j = 0; j < 4; ++j) {
        int q = w * 4 + j;
        int qg = q0 + q;
        float m = -1e30f;
        for (int k = lane; k <= qg; k += 64) m = fmaxf(m, (float)Ssm[q][k]);
#pragma unroll
        for (int o = 32; o > 0; o >>= 1) m = fmaxf(m, __shfl_xor(m, o));
        float ssum = 0.f;
        for (int k = lane; k <= qg; k += 64) {
            float e = __expf(((float)Ssm[q][k] - m) * invtau);
            Ssm[q][k] = (f16)e;
            ssum += e;
        }
#pragma unroll
        for (int o = 32; o > 0; o >>= 1) ssum += __shfl_xor(ssum, o);
        float inv = 1.0f / ssum;
        float* orow = attn + ((size_t)((b * 16 + h) * 1024 + qg) << 10);
        for (int k = lane; k < 1024; k += 64) {
            float val = (k <= qg) ? (float)Ssm[q][k] * inv : 0.0f;
            orow[k] = val;
            Ssm[q][k] = (f16)val;  // normalized P (zeros above diag) for PV
        }
    }
    __syncthreads();

    // ---- phase 3: O(16x64) = P(16x1024) @ V(1024x64); wave w owns d-tile [w*16, w*16+16)
    {
        const int dw = w * 16;
        f32x4 acc = {};
        const int nkt = (q0 + 47) >> 5;  // ceil((qmax+1)/32)
        const f16* Vb = vt16 + ((size_t)((b * 16 + h) * 64 + dw + l16)) * 1024 + quad * 8;
#pragma unroll 4
        for (int kt = 0; kt < nkt; ++kt) {
            const int kb = kt << 5;
            f16x8 a = *(const f16x8*)&Ssm[l16][kb + quad * 8];
            f16x8 bf = *(const f16x8*)(Vb + kb);
            acc = mfma_f16(a, bf, acc);
        }
#pragma unroll
        for (int rg = 0; rg < 4; ++rg)
            oh[(size_t)(b * 1024 + q0 + quad * 4 + rg) * 1024 + h * 64 + dw + l16] =
                (f16)acc[rg];
    }
}

// ----------------------------------------------------------------
extern "C" void kernel_launch(void* const* d_in, const int* in_sizes, int n_in,
                              void* d_out, int out_size, void* d_ws, size_t ws_size,
                              hipStream_t stream) {
    const float* x  = (const float*)d_in[0];
    const float* Wq = (const float*)d_in[2];
    const float* bq = (const float*)d_in[3];
    const float* Wk = (const float*)d_in[4];
    const float* bk = (const float*)d_in[5];
    const float* Wv = (const float*)d_in[6];
    const float* bv = (const float*)d_in[7];
    const float* Wo = (const float*)d_in[8];
    const float* bo = (const float*)d_in[9];
    const float* Wg = (const float*)d_in[10];
    const float* bg = (const float*)d_in[11];
    const float* lt = (const float*)d_in[12];
    float* out = (float*)d_out;
    float* attn = out + (size_t)2 * 1024 * 1024;

    char* ws = (char*)d_ws;
    const size_t KB = (size_t)1 << 10;
    f16*   x16   = (f16*)ws;                     // 4096 KB (2048x1024)
    f16*   w16   = (f16*)(ws + 4096 * KB);       // 6272 KB (Wq|Wk|Wv|Wg-pad 3136x1024)
    f16*   wo16  = (f16*)(ws + 10368 * KB);      // 2048 KB
    f16*   qkv16 = (f16*)(ws + 12416 * KB);      // 12288 KB (Q,K used; V third unused)
    f16*   vt16  = (f16*)(ws + 24704 * KB);      // 4096 KB (V^T per (b*16+h))
    float* gbuf  = (float*)(ws + 28800 * KB);    // 128 KB
    f16*   oh16  = (f16*)(ws + 28928 * KB);      // 4096 KB — total ~32.3 MiB

    cvt_all<<<6208, 256, 0, stream>>>(x, Wq, Wk, Wv, Wo, Wg, x16, w16, wo16);
    gemm128<true, true, true><<<dim3(49, 16), 256, 0, stream>>>(
        x16, w16, qkv16, bq, bk, bv, bg, vt16, gbuf, 1024, 1024, 1024, 3072);
    scores_fused<<<2048, 256, 0, stream>>>(qkv16, vt16, gbuf, lt, attn, oh16);
    gemm128<false, false, false><<<dim3(16, 16), 256, 0, stream>>>(
        oh16, wo16, out, bo, bo, bo, nullptr, nullptr, nullptr, 1024, 1024, 1024, 1024);
}